// Round 11
// baseline (346.904 us; speedup 1.0000x reference)
//
#include <hip/hip_runtime.h>

#define BIGF 3.402823466e38f

typedef __attribute__((ext_vector_type(8))) short bf16x8;
typedef __attribute__((ext_vector_type(4))) float f32x4;

__device__ __forceinline__ void gload_lds16u(const unsigned short* g, unsigned short* lds) {
  __builtin_amdgcn_global_load_lds((const __attribute__((address_space(1))) void*)g,
                                   (__attribute__((address_space(3))) void*)lds, 16, 0, 0);
}

__device__ __forceinline__ unsigned short bf16_rne(float f) {
  unsigned int u = __float_as_uint(f);
  return (unsigned short)((u + 0x7fffu + ((u >> 16) & 1u)) >> 16);
}

// ---------------- K1: transpose + sq + y + delta + bf16 hi/lo packed rows ----------------
// xhl row (per point): 128 bf16 = [hi d0..63 | lo d0..63], stored as 16 chunks of 16B with
// chunk c placed at position c ^ (point&7) (bank-decorrelating swizzle, low-3-bit XOR).
__global__ __launch_bounds__(256) void k1_pre(const float* __restrict__ x, const float* __restrict__ w,
                                              float* __restrict__ sq, float* __restrict__ y,
                                              float* __restrict__ delta, unsigned short* __restrict__ xhl) {
  __shared__ __align__(16) float xt[64][68];
  __shared__ __align__(16) float ws[128][64];
  const int t = threadIdx.x;
  const int bid = blockIdx.x;
  const int b = bid >> 6;
  const int n0 = (bid & 63) << 6;
  const float* xb = x + (size_t)b * 64 * 4096;

#pragma unroll
  for (int rep = 0; rep < 16; ++rep) {
    int id = rep * 256 + t;
    int d = id >> 6, n = id & 63;
    xt[n][d] = xb[(size_t)d * 4096 + n0 + n];
  }
#pragma unroll
  for (int rep = 0; rep < 32; ++rep) {
    int id = rep * 256 + t;
    int u = id >> 6, dd = id & 63;
    ws[u][dd] = w[(u & 63) * 128 + ((u >> 6) << 6) + dd];
  }
  __syncthreads();

  // ---- bf16 hi/lo packed emit: thread t -> point p = t>>2, chunk group cg = t&3 ----
  {
    const int p = t >> 2;
    const int cg = t & 3;
    uint4* orow = (uint4*)xhl + ((size_t)(b << 12) + n0 + p) * 16;
#pragma unroll
    for (int cc = 0; cc < 4; ++cc) {
      const int c = cg * 4 + cc;
      const int kb = (c & 7) * 8;
      const bool lohalf = (c >= 8);
      unsigned int pk[4];
#pragma unroll
      for (int j2 = 0; j2 < 4; ++j2) {
        unsigned short u0, u1;
#pragma unroll
        for (int e = 0; e < 2; ++e) {
          const float xv = xt[p][kb + j2 * 2 + e];
          unsigned short h = bf16_rne(xv);
          unsigned short r;
          if (!lohalf) r = h;
          else r = bf16_rne(xv - __uint_as_float(((unsigned int)h) << 16));
          if (e == 0) u0 = r; else u1 = r;
        }
        pk[j2] = (unsigned int)u0 | ((unsigned int)u1 << 16);
      }
      uint4 v;
      v.x = pk[0]; v.y = pk[1]; v.z = pk[2]; v.w = pk[3];
      orow[c ^ (p & 7)] = v;
    }
  }

  const int p = t & 63;
  const int oc = t >> 6;
  float accy[16], accz[16];
#pragma unroll
  for (int j = 0; j < 16; ++j) { accy[j] = 0.f; accz[j] = 0.f; }

#pragma unroll 4
  for (int d4 = 0; d4 < 16; ++d4) {
    const float4 xv = *(const float4*)&xt[p][d4 * 4];
#pragma unroll
    for (int j = 0; j < 16; ++j) {
      const int o = oc * 16 + j;
      const float4 wy = *(const float4*)&ws[o][d4 * 4];
      const float4 wz = *(const float4*)&ws[o + 64][d4 * 4];
      accy[j] = fmaf(xv.x, wy.x, fmaf(xv.y, wy.y, fmaf(xv.z, wy.z, fmaf(xv.w, wy.w, accy[j]))));
      accz[j] = fmaf(xv.x, wz.x, fmaf(xv.y, wz.y, fmaf(xv.z, wz.z, fmaf(xv.w, wz.w, accz[j]))));
    }
  }

  if (oc == 0) {
    float s = 0.f;
#pragma unroll
    for (int d4 = 0; d4 < 16; ++d4) {
      const float4 v = *(const float4*)&xt[p][d4 * 4];
      s = fmaf(v.x, v.x, fmaf(v.y, v.y, fmaf(v.z, v.z, fmaf(v.w, v.w, s))));
    }
    sq[b * 4096 + n0 + p] = s;
  }

  const size_t row = ((size_t)b * 4096 + n0 + p) * 64 + oc * 16;
#pragma unroll
  for (int j4 = 0; j4 < 4; ++j4) {
    float4 yv = make_float4(accy[j4 * 4], accy[j4 * 4 + 1], accy[j4 * 4 + 2], accy[j4 * 4 + 3]);
    float4 dv = make_float4(accz[j4 * 4] - accy[j4 * 4], accz[j4 * 4 + 1] - accy[j4 * 4 + 1],
                            accz[j4 * 4 + 2] - accy[j4 * 4 + 2], accz[j4 * 4 + 3] - accy[j4 * 4 + 3]);
    *(float4*)&y[row + j4 * 4] = yv;
    *(float4*)&delta[row + j4 * 4] = dv;
  }
}

// ---------------- K2: MFMA pairwise-distance GEMM (bf16 hi/lo) + streaming top-20 ----------------
// R11 = R10 verbatim (205us: drain latency hoisted + parallel shift-insert). k2 untouched
// this round — it is the attribution control while k3 is restructured.
__global__ __launch_bounds__(256, 2) void k2_knn(const unsigned short* __restrict__ xhl,
                                                 const float* __restrict__ sq,
                                                 int* __restrict__ idx_out) {
  // LDS (float words):
  //  [0,4096)      As 16KB (A rows during prologue) -> bufD[12][256] overlay (3072 words)
  //  [4096,12288)  stage slices: wave w at 4096 + w*2048 (32 m-rows x 256B; doubles as dump)
  //  [12288,15360) bufI[12][256]
  //  [15360,15424) thrN[64] (uint bits of running shared 20th per n)
  //  merge overlay: pf @ [0,5120), pi @ [5120,10240)
  __shared__ __align__(16) float smem[15424];
  const int t = threadIdx.x;
  const int lane = t & 63;
  const int w = t >> 6;
  float* BsW = smem + 4096 + (w << 11);
  uint4* BsW4 = (uint4*)BsW;
  const uint4* As4 = (const uint4*)smem;
  unsigned* bufD = (unsigned*)smem;             // [12][256] overlay on dead As
  unsigned* bufI = (unsigned*)(smem + 12288);   // [12][256]
  unsigned* thrNa = (unsigned*)(smem + 15360);
  volatile unsigned* thrNv = (volatile unsigned*)(smem + 15360);

  const int bid = blockIdx.x;
  const int b = bid >> 6;
  const int n0 = (bid & 63) << 6;
  const int pn = lane & 15, q = lane >> 4;
  const int myn = lane;
  const int swz = myn & 7;

  const unsigned short* xr = xhl + ((size_t)(b << 12)) * 128;
  const float* sqb = sq + (b << 12);

  if (t < 64) thrNa[t] = 0x7F7FFFFFu;  // +BIGF bits (d^2 >= 0: uint order == float order)

  // stage A rows (64 points x 256B = 16KB): 16 x 1KB, 4 per wave
  {
    unsigned short* asu = (unsigned short*)smem;
#pragma unroll
    for (int qq = 0; qq < 4; ++qq) {
      const int kk = w * 4 + qq;
      gload_lds16u(xr + (size_t)n0 * 128 + kk * 512 + lane * 8, asu + kk * 512);
    }
  }
  const float sqn = sqb[n0 + myn];
  __builtin_amdgcn_s_waitcnt(0x0F70);  // vmcnt(0)
  __syncthreads();

  // n-side fragments, register-resident: per nt: [hi0, hi1, lo0, lo1]
  bf16x8 bfr[4][4];
#pragma unroll
  for (int nt = 0; nt < 4; ++nt)
#pragma unroll
    for (int j = 0; j < 4; ++j)
      bfr[nt][j] = *reinterpret_cast<const bf16x8*>(&As4[((nt << 4) + pn) * 16 + (((j << 2) + q) ^ (pn & 7))]);
  __syncthreads();  // all waves done reading As before any accept-buffer write overlays it

  float kd[20];
  int ki[20];
#pragma unroll
  for (int s = 0; s < 20; ++s) { kd[s] = BIGF; ki[s] = -1; }
  int cnt = 0;

  // parallel shift-insert: comparisons all vs the OLD list (independent); s descends so
  // every kd[s-1]/kd[s] read is pre-insert. Semantics identical to the serial carry form.
  auto ins = [&](float vd, int vi) {
#pragma unroll
    for (int s = 19; s >= 1; --s) {
      const bool a = vd < kd[s - 1];
      const bool bb = vd < kd[s];
      kd[s] = a ? kd[s - 1] : (bb ? vd : kd[s]);
      ki[s] = a ? ki[s - 1] : (bb ? vi : ki[s]);
    }
    const bool b0 = vd < kd[0];
    kd[0] = b0 ? vd : kd[0];
    ki[0] = b0 ? vi : ki[0];
  };

  auto drain = [&]() {
    // hoisted, independent, conflict-free loads: one latency exposure for the whole batch
    unsigned vD[12], vI[12];
#pragma unroll
    for (int j = 0; j < 12; ++j) { vD[j] = bufD[j * 256 + t]; vI[j] = bufI[j * 256 + t]; }
#pragma unroll
    for (int j = 0; j < 12; ++j) {
      if (__any(j < cnt)) {
        if (j < cnt) {
          const float dv = __uint_as_float(vD[j]);
          if (dv < kd[19]) ins(dv, (int)vI[j]);
        }
      }
    }
    cnt = 0;
    atomicMin(&thrNa[myn], __float_as_uint(kd[19]));  // publish (monotone decreasing)
  };

  const f32x4 zero4 = {0.f, 0.f, 0.f, 0.f};
  f32x4 acc[4][2];
#pragma unroll
  for (int nt = 0; nt < 4; ++nt) { acc[nt][0] = zero4; acc[nt][1] = zero4; }

  for (int kt = 0; kt < 32; ++kt) {
    const int mbase = (w + 4 * kt) << 5;
    // stage m rows (32 points x 256B = 8KB): 8 x 1KB
    {
      unsigned short* bsu = (unsigned short*)BsW;
      const unsigned short* src = xr + (size_t)mbase * 128;
#pragma unroll
      for (int k = 0; k < 8; ++k) gload_lds16u(src + k * 512 + lane * 8, bsu + k * 512);
    }
    const f32x4 sqm0 = *(const f32x4*)&sqb[mbase + (q << 2)];
    const f32x4 sqm1 = *(const f32x4*)&sqb[mbase + 16 + (q << 2)];
    __builtin_amdgcn_s_waitcnt(0x0F70);  // vmcnt(0)

    // shared per-n gate: single conflict-free read; refreshed again after every drain
    float thr2 = (fminf(__uint_as_float(thrNv[myn]), kd[19]) - sqn) + 0.001f;

#pragma unroll
    for (int mt = 0; mt < 2; ++mt) {
      bf16x8 afr[4];
#pragma unroll
      for (int j = 0; j < 4; ++j)
        afr[j] = *reinterpret_cast<const bf16x8*>(&BsW4[((mt << 4) + pn) * 16 + (((j << 2) + q) ^ (pn & 7))]);
#pragma unroll
      for (int nt = 0; nt < 4; ++nt) {
        f32x4 a = acc[nt][mt];
        a = __builtin_amdgcn_mfma_f32_16x16x32_bf16(afr[0], bfr[nt][0], a, 0, 0, 0);  // hi_m*hi_n
        a = __builtin_amdgcn_mfma_f32_16x16x32_bf16(afr[1], bfr[nt][1], a, 0, 0, 0);
        a = __builtin_amdgcn_mfma_f32_16x16x32_bf16(afr[0], bfr[nt][2], a, 0, 0, 0);  // hi_m*lo_n
        a = __builtin_amdgcn_mfma_f32_16x16x32_bf16(afr[1], bfr[nt][3], a, 0, 0, 0);
        a = __builtin_amdgcn_mfma_f32_16x16x32_bf16(afr[2], bfr[nt][0], a, 0, 0, 0);  // lo_m*hi_n
        a = __builtin_amdgcn_mfma_f32_16x16x32_bf16(afr[3], bfr[nt][1], a, 0, 0, 0);
        acc[nt][mt] = a;
      }
    }

    // dump: value = sq_m - 2*dot, row n, m-quad g=(mt*4+q) at chunk g^(n&7)
#pragma unroll
    for (int nt = 0; nt < 4; ++nt) {
#pragma unroll
      for (int mt = 0; mt < 2; ++mt) {
        const int n = (nt << 4) + pn;
        const int g = (mt << 2) + q;
        const int pc = g ^ (n & 7);
        const f32x4 sv = mt ? sqm1 : sqm0;
        f32x4 dv = sv - 2.0f * acc[nt][mt];
        *(f32x4*)&BsW[(n << 5) + (pc << 2)] = dv;
        acc[nt][mt] = zero4;
      }
    }

    // scan own row (myn): 2 halves x 4 chunks, loads batched 4-at-a-time (latency overlap),
    // v-space min4 pre-gate, accepts -> SoA buffer; thr2 re-tightened after every drain.
    // Ascending-m order + strict < preserves the reference's lowest-index-first tie-break.
#pragma unroll 1
    for (int half = 0; half < 2; ++half) {
      const int cb = half << 2;
      const float4 v0 = *(const float4*)&BsW[(myn << 5) + (((cb + 0) ^ swz) << 2)];
      const float4 v1 = *(const float4*)&BsW[(myn << 5) + (((cb + 1) ^ swz) << 2)];
      const float4 v2 = *(const float4*)&BsW[(myn << 5) + (((cb + 2) ^ swz) << 2)];
      const float4 v3 = *(const float4*)&BsW[(myn << 5) + (((cb + 3) ^ swz) << 2)];
#pragma unroll
      for (int cc = 0; cc < 4; ++cc) {
        const float4 v = (cc == 0) ? v0 : (cc == 1) ? v1 : (cc == 2) ? v2 : v3;
        const int mb = mbase + ((cb + cc) << 2);
        const float mn = fminf(fminf(v.x, v.y), fminf(v.z, v.w));
        if (mn < thr2) {
          if (v.x < thr2) { bufD[cnt * 256 + t] = __float_as_uint(sqn + v.x); bufI[cnt * 256 + t] = (unsigned)mb; cnt++; }
          if (v.y < thr2) { bufD[cnt * 256 + t] = __float_as_uint(sqn + v.y); bufI[cnt * 256 + t] = (unsigned)(mb + 1); cnt++; }
          if (v.z < thr2) { bufD[cnt * 256 + t] = __float_as_uint(sqn + v.z); bufI[cnt * 256 + t] = (unsigned)(mb + 2); cnt++; }
          if (v.w < thr2) { bufD[cnt * 256 + t] = __float_as_uint(sqn + v.w); bufI[cnt * 256 + t] = (unsigned)(mb + 3); cnt++; }
        }
        if (__any(cnt > 8)) {
          drain();  // cap 12: pre<=8, chunk adds <=4
          thr2 = fminf(thr2, (fminf(__uint_as_float(thrNv[myn]), kd[19]) - sqn) + 0.001f);
        }
      }
    }
  }
  drain();

  // merge the 4 waves' partial lists (LDS overlay; bufs/stage dead, thrN untouched)
  __syncthreads();
  float* pf = smem;                 // [4][20][64]
  int* pi = (int*)(smem + 5120);    // [4][20][64]
#pragma unroll
  for (int s = 0; s < 20; ++s) {
    pf[(w * 20 + s) * 64 + lane] = kd[s];
    pi[(w * 20 + s) * 64 + lane] = ki[s];
  }
  __syncthreads();
  if (w == 0) {
    auto insTie = [&](float vd, int vi) {
#pragma unroll
      for (int s = 0; s < 20; ++s) {
        const float od = kd[s];
        const int oi = ki[s];
        const bool lt = (vd < od) || (vd == od && vi < oi);
        kd[s] = lt ? vd : od;
        ki[s] = lt ? vi : oi;
        vd = lt ? od : vd;
        vi = lt ? oi : vi;
      }
    };
    for (int ww = 1; ww < 4; ++ww) {
#pragma unroll 1
      for (int s = 0; s < 20; ++s) {
        const float dv = pf[(ww * 20 + s) * 64 + lane];
        const int iv = pi[(ww * 20 + s) * 64 + lane];
        if (dv < kd[19] || (dv == kd[19] && iv < ki[19])) insTie(dv, iv);
      }
    }
    int* orow = idx_out + ((size_t)(b << 12) + n0 + lane) * 20;
#pragma unroll
    for (int s = 0; s < 20; ++s) orow[s] = ki[s];
  }
}

// ---------------- K3: gathered neighbor max + h + BN stats ----------------
// R11: OCCUPANCY FIX. Old grid=512 capped the latency-bound random gather (20 x 256B y-rows
// per point, ~500cy each) at 2 blocks/CU (grid-limited, not resource-limited). New: grid=2048
// (16 points/block, 4/wave) -> 8 blocks/CU, 32 waves/CU = 4x TLP. Plus XCD-aware mapping:
// bid&7 selects the batch, so all 256 blocks of batch b land on XCD b (round-robin dispatch)
// and the batch's 1MB y-slice stays L2-resident per XCD (every y row is re-read ~20x).
__global__ __launch_bounds__(256) void k3_gather(const float* __restrict__ y,
                                                 const float* __restrict__ delta,
                                                 const int* __restrict__ idx,
                                                 float* __restrict__ h,
                                                 float* __restrict__ sums,
                                                 float* __restrict__ sumsq) {
  const int t = threadIdx.x;
  const int lane = t & 63;  // channel o
  const int w = t >> 6;
  const int bid = blockIdx.x;
  const int blk = (bid & 7) * 256 + (bid >> 3);  // batch = blk>>8 = bid&7 -> XCD-local y slice
  float s1 = 0.f, s2 = 0.f;
  for (int p = 0; p < 4; ++p) {
    const int ng = blk * 16 + w * 4 + p;
    const int b = ng >> 12;
    const int* row = idx + (size_t)ng * 20;
    float mx = -BIGF;
#pragma unroll
    for (int kk = 0; kk < 20; ++kk) {
      const int nbr = row[kk];
      mx = fmaxf(mx, y[((size_t)(b << 12) + nbr) * 64 + lane]);
    }
    const float hv = mx + delta[(size_t)ng * 64 + lane];
    h[(size_t)ng * 64 + lane] = hv;
    s1 += hv;
    s2 += hv * hv;
  }
  __shared__ float r1[4][64], r2[4][64];
  r1[w][lane] = s1;
  r2[w][lane] = s2;
  __syncthreads();
  if (w == 0) {
    const float a = r1[0][lane] + r1[1][lane] + r1[2][lane] + r1[3][lane];
    const float c = r2[0][lane] + r2[1][lane] + r2[2][lane] + r2[3][lane];
    atomicAdd(&sums[lane], a);
    atomicAdd(&sumsq[lane], c);
  }
}

// ---------------- K4: BN finalize + exact GELU + transposed write ----------------
__global__ __launch_bounds__(256) void k4_bn(const float* __restrict__ h,
                                             const float* __restrict__ sums,
                                             const float* __restrict__ sumsq,
                                             const float* __restrict__ gamma,
                                             const float* __restrict__ beta,
                                             float* __restrict__ out) {
  __shared__ float tile[64][65];
  const int bid = blockIdx.x;
  const int b = bid >> 6;
  const int n0 = (bid & 63) << 6;
  const int t = threadIdx.x;
  const int o = t & 63;
#pragma unroll
  for (int it = 0; it < 16; ++it) {
    const int n = (t >> 6) * 16 + it;
    tile[n][o] = h[(((size_t)b << 12) + n0 + n) * 64 + o];
  }
  __syncthreads();
  const int j = t & 63;
#pragma unroll
  for (int it = 0; it < 16; ++it) {
    const int oo = (t >> 6) * 16 + it;
    const float mean = sums[oo] * (1.0f / 32768.0f);
    const float var = sumsq[oo] * (1.0f / 32768.0f) - mean * mean;
    const float sc = gamma[oo] / sqrtf(var + 1e-5f);
    const float hv = tile[j][oo];
    const float hn = (hv - mean) * sc + beta[oo];
    const float g = 0.5f * hn * (1.0f + erff(hn * 0.70710678118654752f));
    out[((size_t)(b * 64 + oo)) * 4096 + n0 + j] = g;
  }
}

extern "C" void kernel_launch(void* const* d_in, const int* in_sizes, int n_in,
                              void* d_out, int out_size, void* d_ws, size_t ws_size,
                              hipStream_t stream) {
  const float* x = (const float*)d_in[0];
  const float* w = (const float*)d_in[1];
  const float* gamma = (const float*)d_in[2];
  const float* beta = (const float*)d_in[3];
  float* out = (float*)d_out;

  float* sq_ws = (float*)d_ws;               // 32768
  float* y_ws = sq_ws + 32768;               // 8 MB
  float* delta_ws = y_ws + 2097152;          // 8 MB
  float* h_ws = delta_ws + 2097152;          // 8 MB (k3/k4) — overlaid by xhl in k1/k2
  int* idx_ws = (int*)(h_ws + 2097152);      // 2.6 MB
  float* sums = (float*)(idx_ws + 655360);   // 64
  float* sumsq = sums + 64;                  // 64
  unsigned short* xhl = (unsigned short*)h_ws;  // 8 MB bf16 hi/lo rows (dead after k2)

  hipMemsetAsync(sums, 0, 2 * 64 * sizeof(float), stream);
  k1_pre<<<512, 256, 0, stream>>>(x, w, sq_ws, y_ws, delta_ws, xhl);
  k2_knn<<<512, 256, 0, stream>>>(xhl, sq_ws, idx_ws);
  k3_gather<<<2048, 256, 0, stream>>>(y_ws, delta_ws, idx_ws, h_ws, sums, sumsq);
  k4_bn<<<512, 256, 0, stream>>>(h_ws, sums, sumsq, gamma, beta, out);
}

// Round 12
// 323.015 us; speedup vs baseline: 1.0740x; 1.0740x over previous
//
#include <hip/hip_runtime.h>

#define BIGF 3.402823466e38f

typedef __attribute__((ext_vector_type(8))) short bf16x8;
typedef __attribute__((ext_vector_type(4))) float f32x4;

__device__ __forceinline__ void gload_lds16u(const unsigned short* g, unsigned short* lds) {
  __builtin_amdgcn_global_load_lds((const __attribute__((address_space(1))) void*)g,
                                   (__attribute__((address_space(3))) void*)lds, 16, 0, 0);
}

__device__ __forceinline__ unsigned short bf16_rne(float f) {
  unsigned int u = __float_as_uint(f);
  return (unsigned short)((u + 0x7fffu + ((u >> 16) & 1u)) >> 16);
}

// ---------------- K1: transpose + sq + y + delta + bf16 hi/lo packed rows ----------------
// xhl row (per point): 128 bf16 = [hi d0..63 | lo d0..63], stored as 16 chunks of 16B with
// chunk c placed at position c ^ (point&7) (bank-decorrelating swizzle, low-3-bit XOR).
__global__ __launch_bounds__(256) void k1_pre(const float* __restrict__ x, const float* __restrict__ w,
                                              float* __restrict__ sq, float* __restrict__ y,
                                              float* __restrict__ delta, unsigned short* __restrict__ xhl) {
  __shared__ __align__(16) float xt[64][68];
  __shared__ __align__(16) float ws[128][64];
  const int t = threadIdx.x;
  const int bid = blockIdx.x;
  const int b = bid >> 6;
  const int n0 = (bid & 63) << 6;
  const float* xb = x + (size_t)b * 64 * 4096;

#pragma unroll
  for (int rep = 0; rep < 16; ++rep) {
    int id = rep * 256 + t;
    int d = id >> 6, n = id & 63;
    xt[n][d] = xb[(size_t)d * 4096 + n0 + n];
  }
#pragma unroll
  for (int rep = 0; rep < 32; ++rep) {
    int id = rep * 256 + t;
    int u = id >> 6, dd = id & 63;
    ws[u][dd] = w[(u & 63) * 128 + ((u >> 6) << 6) + dd];
  }
  __syncthreads();

  // ---- bf16 hi/lo packed emit: thread t -> point p = t>>2, chunk group cg = t&3 ----
  {
    const int p = t >> 2;
    const int cg = t & 3;
    uint4* orow = (uint4*)xhl + ((size_t)(b << 12) + n0 + p) * 16;
#pragma unroll
    for (int cc = 0; cc < 4; ++cc) {
      const int c = cg * 4 + cc;
      const int kb = (c & 7) * 8;
      const bool lohalf = (c >= 8);
      unsigned int pk[4];
#pragma unroll
      for (int j2 = 0; j2 < 4; ++j2) {
        unsigned short u0, u1;
#pragma unroll
        for (int e = 0; e < 2; ++e) {
          const float xv = xt[p][kb + j2 * 2 + e];
          unsigned short h = bf16_rne(xv);
          unsigned short r;
          if (!lohalf) r = h;
          else r = bf16_rne(xv - __uint_as_float(((unsigned int)h) << 16));
          if (e == 0) u0 = r; else u1 = r;
        }
        pk[j2] = (unsigned int)u0 | ((unsigned int)u1 << 16);
      }
      uint4 v;
      v.x = pk[0]; v.y = pk[1]; v.z = pk[2]; v.w = pk[3];
      orow[c ^ (p & 7)] = v;
    }
  }

  const int p = t & 63;
  const int oc = t >> 6;
  float accy[16], accz[16];
#pragma unroll
  for (int j = 0; j < 16; ++j) { accy[j] = 0.f; accz[j] = 0.f; }

#pragma unroll 4
  for (int d4 = 0; d4 < 16; ++d4) {
    const float4 xv = *(const float4*)&xt[p][d4 * 4];
#pragma unroll
    for (int j = 0; j < 16; ++j) {
      const int o = oc * 16 + j;
      const float4 wy = *(const float4*)&ws[o][d4 * 4];
      const float4 wz = *(const float4*)&ws[o + 64][d4 * 4];
      accy[j] = fmaf(xv.x, wy.x, fmaf(xv.y, wy.y, fmaf(xv.z, wy.z, fmaf(xv.w, wy.w, accy[j]))));
      accz[j] = fmaf(xv.x, wz.x, fmaf(xv.y, wz.y, fmaf(xv.z, wz.z, fmaf(xv.w, wz.w, accz[j]))));
    }
  }

  if (oc == 0) {
    float s = 0.f;
#pragma unroll
    for (int d4 = 0; d4 < 16; ++d4) {
      const float4 v = *(const float4*)&xt[p][d4 * 4];
      s = fmaf(v.x, v.x, fmaf(v.y, v.y, fmaf(v.z, v.z, fmaf(v.w, v.w, s))));
    }
    sq[b * 4096 + n0 + p] = s;
  }

  const size_t row = ((size_t)b * 4096 + n0 + p) * 64 + oc * 16;
#pragma unroll
  for (int j4 = 0; j4 < 4; ++j4) {
    float4 yv = make_float4(accy[j4 * 4], accy[j4 * 4 + 1], accy[j4 * 4 + 2], accy[j4 * 4 + 3]);
    float4 dv = make_float4(accz[j4 * 4] - accy[j4 * 4], accz[j4 * 4 + 1] - accy[j4 * 4 + 1],
                            accz[j4 * 4 + 2] - accy[j4 * 4 + 2], accz[j4 * 4 + 3] - accy[j4 * 4 + 3]);
    *(float4*)&y[row + j4 * 4] = yv;
    *(float4*)&delta[row + j4 * 4] = dv;
  }
}

// ---------------- K2: MFMA pairwise-distance GEMM (bf16 hi/lo) + streaming top-20 ----------------
// R12 = R10 verbatim (205us: drain latency hoisted + parallel shift-insert). Untouched —
// attribution control.
__global__ __launch_bounds__(256, 2) void k2_knn(const unsigned short* __restrict__ xhl,
                                                 const float* __restrict__ sq,
                                                 int* __restrict__ idx_out) {
  // LDS (float words):
  //  [0,4096)      As 16KB (A rows during prologue) -> bufD[12][256] overlay (3072 words)
  //  [4096,12288)  stage slices: wave w at 4096 + w*2048 (32 m-rows x 256B; doubles as dump)
  //  [12288,15360) bufI[12][256]
  //  [15360,15424) thrN[64] (uint bits of running shared 20th per n)
  //  merge overlay: pf @ [0,5120), pi @ [5120,10240)
  __shared__ __align__(16) float smem[15424];
  const int t = threadIdx.x;
  const int lane = t & 63;
  const int w = t >> 6;
  float* BsW = smem + 4096 + (w << 11);
  uint4* BsW4 = (uint4*)BsW;
  const uint4* As4 = (const uint4*)smem;
  unsigned* bufD = (unsigned*)smem;             // [12][256] overlay on dead As
  unsigned* bufI = (unsigned*)(smem + 12288);   // [12][256]
  unsigned* thrNa = (unsigned*)(smem + 15360);
  volatile unsigned* thrNv = (volatile unsigned*)(smem + 15360);

  const int bid = blockIdx.x;
  const int b = bid >> 6;
  const int n0 = (bid & 63) << 6;
  const int pn = lane & 15, q = lane >> 4;
  const int myn = lane;
  const int swz = myn & 7;

  const unsigned short* xr = xhl + ((size_t)(b << 12)) * 128;
  const float* sqb = sq + (b << 12);

  if (t < 64) thrNa[t] = 0x7F7FFFFFu;  // +BIGF bits (d^2 >= 0: uint order == float order)

  // stage A rows (64 points x 256B = 16KB): 16 x 1KB, 4 per wave
  {
    unsigned short* asu = (unsigned short*)smem;
#pragma unroll
    for (int qq = 0; qq < 4; ++qq) {
      const int kk = w * 4 + qq;
      gload_lds16u(xr + (size_t)n0 * 128 + kk * 512 + lane * 8, asu + kk * 512);
    }
  }
  const float sqn = sqb[n0 + myn];
  __builtin_amdgcn_s_waitcnt(0x0F70);  // vmcnt(0)
  __syncthreads();

  // n-side fragments, register-resident: per nt: [hi0, hi1, lo0, lo1]
  bf16x8 bfr[4][4];
#pragma unroll
  for (int nt = 0; nt < 4; ++nt)
#pragma unroll
    for (int j = 0; j < 4; ++j)
      bfr[nt][j] = *reinterpret_cast<const bf16x8*>(&As4[((nt << 4) + pn) * 16 + (((j << 2) + q) ^ (pn & 7))]);
  __syncthreads();  // all waves done reading As before any accept-buffer write overlays it

  float kd[20];
  int ki[20];
#pragma unroll
  for (int s = 0; s < 20; ++s) { kd[s] = BIGF; ki[s] = -1; }
  int cnt = 0;

  // parallel shift-insert: comparisons all vs the OLD list (independent); s descends so
  // every kd[s-1]/kd[s] read is pre-insert. Semantics identical to the serial carry form.
  auto ins = [&](float vd, int vi) {
#pragma unroll
    for (int s = 19; s >= 1; --s) {
      const bool a = vd < kd[s - 1];
      const bool bb = vd < kd[s];
      kd[s] = a ? kd[s - 1] : (bb ? vd : kd[s]);
      ki[s] = a ? ki[s - 1] : (bb ? vi : ki[s]);
    }
    const bool b0 = vd < kd[0];
    kd[0] = b0 ? vd : kd[0];
    ki[0] = b0 ? vi : ki[0];
  };

  auto drain = [&]() {
    // hoisted, independent, conflict-free loads: one latency exposure for the whole batch
    unsigned vD[12], vI[12];
#pragma unroll
    for (int j = 0; j < 12; ++j) { vD[j] = bufD[j * 256 + t]; vI[j] = bufI[j * 256 + t]; }
#pragma unroll
    for (int j = 0; j < 12; ++j) {
      if (__any(j < cnt)) {
        if (j < cnt) {
          const float dv = __uint_as_float(vD[j]);
          if (dv < kd[19]) ins(dv, (int)vI[j]);
        }
      }
    }
    cnt = 0;
    atomicMin(&thrNa[myn], __float_as_uint(kd[19]));  // publish (monotone decreasing)
  };

  const f32x4 zero4 = {0.f, 0.f, 0.f, 0.f};
  f32x4 acc[4][2];
#pragma unroll
  for (int nt = 0; nt < 4; ++nt) { acc[nt][0] = zero4; acc[nt][1] = zero4; }

  for (int kt = 0; kt < 32; ++kt) {
    const int mbase = (w + 4 * kt) << 5;
    // stage m rows (32 points x 256B = 8KB): 8 x 1KB
    {
      unsigned short* bsu = (unsigned short*)BsW;
      const unsigned short* src = xr + (size_t)mbase * 128;
#pragma unroll
      for (int k = 0; k < 8; ++k) gload_lds16u(src + k * 512 + lane * 8, bsu + k * 512);
    }
    const f32x4 sqm0 = *(const f32x4*)&sqb[mbase + (q << 2)];
    const f32x4 sqm1 = *(const f32x4*)&sqb[mbase + 16 + (q << 2)];
    __builtin_amdgcn_s_waitcnt(0x0F70);  // vmcnt(0)

    // shared per-n gate: single conflict-free read; refreshed again after every drain
    float thr2 = (fminf(__uint_as_float(thrNv[myn]), kd[19]) - sqn) + 0.001f;

#pragma unroll
    for (int mt = 0; mt < 2; ++mt) {
      bf16x8 afr[4];
#pragma unroll
      for (int j = 0; j < 4; ++j)
        afr[j] = *reinterpret_cast<const bf16x8*>(&BsW4[((mt << 4) + pn) * 16 + (((j << 2) + q) ^ (pn & 7))]);
#pragma unroll
      for (int nt = 0; nt < 4; ++nt) {
        f32x4 a = acc[nt][mt];
        a = __builtin_amdgcn_mfma_f32_16x16x32_bf16(afr[0], bfr[nt][0], a, 0, 0, 0);  // hi_m*hi_n
        a = __builtin_amdgcn_mfma_f32_16x16x32_bf16(afr[1], bfr[nt][1], a, 0, 0, 0);
        a = __builtin_amdgcn_mfma_f32_16x16x32_bf16(afr[0], bfr[nt][2], a, 0, 0, 0);  // hi_m*lo_n
        a = __builtin_amdgcn_mfma_f32_16x16x32_bf16(afr[1], bfr[nt][3], a, 0, 0, 0);
        a = __builtin_amdgcn_mfma_f32_16x16x32_bf16(afr[2], bfr[nt][0], a, 0, 0, 0);  // lo_m*hi_n
        a = __builtin_amdgcn_mfma_f32_16x16x32_bf16(afr[3], bfr[nt][1], a, 0, 0, 0);
        acc[nt][mt] = a;
      }
    }

    // dump: value = sq_m - 2*dot, row n, m-quad g=(mt*4+q) at chunk g^(n&7)
#pragma unroll
    for (int nt = 0; nt < 4; ++nt) {
#pragma unroll
      for (int mt = 0; mt < 2; ++mt) {
        const int n = (nt << 4) + pn;
        const int g = (mt << 2) + q;
        const int pc = g ^ (n & 7);
        const f32x4 sv = mt ? sqm1 : sqm0;
        f32x4 dv = sv - 2.0f * acc[nt][mt];
        *(f32x4*)&BsW[(n << 5) + (pc << 2)] = dv;
        acc[nt][mt] = zero4;
      }
    }

    // scan own row (myn): 2 halves x 4 chunks, loads batched 4-at-a-time (latency overlap),
    // v-space min4 pre-gate, accepts -> SoA buffer; thr2 re-tightened after every drain.
    // Ascending-m order + strict < preserves the reference's lowest-index-first tie-break.
#pragma unroll 1
    for (int half = 0; half < 2; ++half) {
      const int cb = half << 2;
      const float4 v0 = *(const float4*)&BsW[(myn << 5) + (((cb + 0) ^ swz) << 2)];
      const float4 v1 = *(const float4*)&BsW[(myn << 5) + (((cb + 1) ^ swz) << 2)];
      const float4 v2 = *(const float4*)&BsW[(myn << 5) + (((cb + 2) ^ swz) << 2)];
      const float4 v3 = *(const float4*)&BsW[(myn << 5) + (((cb + 3) ^ swz) << 2)];
#pragma unroll
      for (int cc = 0; cc < 4; ++cc) {
        const float4 v = (cc == 0) ? v0 : (cc == 1) ? v1 : (cc == 2) ? v2 : v3;
        const int mb = mbase + ((cb + cc) << 2);
        const float mn = fminf(fminf(v.x, v.y), fminf(v.z, v.w));
        if (mn < thr2) {
          if (v.x < thr2) { bufD[cnt * 256 + t] = __float_as_uint(sqn + v.x); bufI[cnt * 256 + t] = (unsigned)mb; cnt++; }
          if (v.y < thr2) { bufD[cnt * 256 + t] = __float_as_uint(sqn + v.y); bufI[cnt * 256 + t] = (unsigned)(mb + 1); cnt++; }
          if (v.z < thr2) { bufD[cnt * 256 + t] = __float_as_uint(sqn + v.z); bufI[cnt * 256 + t] = (unsigned)(mb + 2); cnt++; }
          if (v.w < thr2) { bufD[cnt * 256 + t] = __float_as_uint(sqn + v.w); bufI[cnt * 256 + t] = (unsigned)(mb + 3); cnt++; }
        }
        if (__any(cnt > 8)) {
          drain();  // cap 12: pre<=8, chunk adds <=4
          thr2 = fminf(thr2, (fminf(__uint_as_float(thrNv[myn]), kd[19]) - sqn) + 0.001f);
        }
      }
    }
  }
  drain();

  // merge the 4 waves' partial lists (LDS overlay; bufs/stage dead, thrN untouched)
  __syncthreads();
  float* pf = smem;                 // [4][20][64]
  int* pi = (int*)(smem + 5120);    // [4][20][64]
#pragma unroll
  for (int s = 0; s < 20; ++s) {
    pf[(w * 20 + s) * 64 + lane] = kd[s];
    pi[(w * 20 + s) * 64 + lane] = ki[s];
  }
  __syncthreads();
  if (w == 0) {
    auto insTie = [&](float vd, int vi) {
#pragma unroll
      for (int s = 0; s < 20; ++s) {
        const float od = kd[s];
        const int oi = ki[s];
        const bool lt = (vd < od) || (vd == od && vi < oi);
        kd[s] = lt ? vd : od;
        ki[s] = lt ? vi : oi;
        vd = lt ? od : vd;
        vi = lt ? oi : vi;
      }
    };
    for (int ww = 1; ww < 4; ++ww) {
#pragma unroll 1
      for (int s = 0; s < 20; ++s) {
        const float dv = pf[(ww * 20 + s) * 64 + lane];
        const int iv = pi[(ww * 20 + s) * 64 + lane];
        if (dv < kd[19] || (dv == kd[19] && iv < ki[19])) insTie(dv, iv);
      }
    }
    int* orow = idx_out + ((size_t)(b << 12) + n0 + lane) * 20;
#pragma unroll
    for (int s = 0; s < 20; ++s) orow[s] = ki[s];
  }
}

// ---------------- K3: gathered neighbor max + h + BN stats ----------------
// R12: revert R11's XCD remap (dispatch->XCD mapping is undefined; the remap also scattered
// the sequential delta/h streams). Single delta vs R10: grid 512 -> 1024 with SEQUENTIAL
// mapping (32 points/block, 8 per wave) -> 4 blocks/CU, 16 waves/CU for the latency-bound
// random gather, same memory-access ordering as R10.
__global__ __launch_bounds__(256) void k3_gather(const float* __restrict__ y,
                                                 const float* __restrict__ delta,
                                                 const int* __restrict__ idx,
                                                 float* __restrict__ h,
                                                 float* __restrict__ sums,
                                                 float* __restrict__ sumsq) {
  const int t = threadIdx.x;
  const int lane = t & 63;  // channel o
  const int w = t >> 6;
  const int blk = blockIdx.x;
  float s1 = 0.f, s2 = 0.f;
  for (int p = 0; p < 8; ++p) {
    const int ng = blk * 32 + w * 8 + p;
    const int b = ng >> 12;
    const int* row = idx + (size_t)ng * 20;
    float mx = -BIGF;
#pragma unroll
    for (int kk = 0; kk < 20; ++kk) {
      const int nbr = row[kk];
      mx = fmaxf(mx, y[((size_t)(b << 12) + nbr) * 64 + lane]);
    }
    const float hv = mx + delta[(size_t)ng * 64 + lane];
    h[(size_t)ng * 64 + lane] = hv;
    s1 += hv;
    s2 += hv * hv;
  }
  __shared__ float r1[4][64], r2[4][64];
  r1[w][lane] = s1;
  r2[w][lane] = s2;
  __syncthreads();
  if (w == 0) {
    const float a = r1[0][lane] + r1[1][lane] + r1[2][lane] + r1[3][lane];
    const float c = r2[0][lane] + r2[1][lane] + r2[2][lane] + r2[3][lane];
    atomicAdd(&sums[lane], a);
    atomicAdd(&sumsq[lane], c);
  }
}

// ---------------- K4: BN finalize + exact GELU + transposed write ----------------
__global__ __launch_bounds__(256) void k4_bn(const float* __restrict__ h,
                                             const float* __restrict__ sums,
                                             const float* __restrict__ sumsq,
                                             const float* __restrict__ gamma,
                                             const float* __restrict__ beta,
                                             float* __restrict__ out) {
  __shared__ float tile[64][65];
  const int bid = blockIdx.x;
  const int b = bid >> 6;
  const int n0 = (bid & 63) << 6;
  const int t = threadIdx.x;
  const int o = t & 63;
#pragma unroll
  for (int it = 0; it < 16; ++it) {
    const int n = (t >> 6) * 16 + it;
    tile[n][o] = h[(((size_t)b << 12) + n0 + n) * 64 + o];
  }
  __syncthreads();
  const int j = t & 63;
#pragma unroll
  for (int it = 0; it < 16; ++it) {
    const int oo = (t >> 6) * 16 + it;
    const float mean = sums[oo] * (1.0f / 32768.0f);
    const float var = sumsq[oo] * (1.0f / 32768.0f) - mean * mean;
    const float sc = gamma[oo] / sqrtf(var + 1e-5f);
    const float hv = tile[j][oo];
    const float hn = (hv - mean) * sc + beta[oo];
    const float g = 0.5f * hn * (1.0f + erff(hn * 0.70710678118654752f));
    out[((size_t)(b * 64 + oo)) * 4096 + n0 + j] = g;
  }
}

extern "C" void kernel_launch(void* const* d_in, const int* in_sizes, int n_in,
                              void* d_out, int out_size, void* d_ws, size_t ws_size,
                              hipStream_t stream) {
  const float* x = (const float*)d_in[0];
  const float* w = (const float*)d_in[1];
  const float* gamma = (const float*)d_in[2];
  const float* beta = (const float*)d_in[3];
  float* out = (float*)d_out;

  float* sq_ws = (float*)d_ws;               // 32768
  float* y_ws = sq_ws + 32768;               // 8 MB
  float* delta_ws = y_ws + 2097152;          // 8 MB
  float* h_ws = delta_ws + 2097152;          // 8 MB (k3/k4) — overlaid by xhl in k1/k2
  int* idx_ws = (int*)(h_ws + 2097152);      // 2.6 MB
  float* sums = (float*)(idx_ws + 655360);   // 64
  float* sumsq = sums + 64;                  // 64
  unsigned short* xhl = (unsigned short*)h_ws;  // 8 MB bf16 hi/lo rows (dead after k2)

  hipMemsetAsync(sums, 0, 2 * 64 * sizeof(float), stream);
  k1_pre<<<512, 256, 0, stream>>>(x, w, sq_ws, y_ws, delta_ws, xhl);
  k2_knn<<<512, 256, 0, stream>>>(xhl, sq_ws, idx_ws);
  k3_gather<<<1024, 256, 0, stream>>>(y_ws, delta_ws, idx_ws, h_ws, sums, sumsq);
  k4_bn<<<512, 256, 0, stream>>>(h_ws, sums, sumsq, gamma, beta, out);
}

// Round 13
// 314.044 us; speedup vs baseline: 1.1046x; 1.0286x over previous
//
#include <hip/hip_runtime.h>

#define BIGF 3.402823466e38f

typedef __attribute__((ext_vector_type(8))) short bf16x8;
typedef __attribute__((ext_vector_type(4))) float f32x4;

__device__ __forceinline__ void gload_lds16u(const unsigned short* g, unsigned short* lds) {
  __builtin_amdgcn_global_load_lds((const __attribute__((address_space(1))) void*)g,
                                   (__attribute__((address_space(3))) void*)lds, 16, 0, 0);
}

__device__ __forceinline__ unsigned short bf16_rne(float f) {
  unsigned int u = __float_as_uint(f);
  return (unsigned short)((u + 0x7fffu + ((u >> 16) & 1u)) >> 16);
}

// ---------------- K1: transpose + sq + y + delta + bf16 hi/lo packed rows ----------------
// xhl row (per point): 128 bf16 = [hi d0..63 | lo d0..63], stored as 16 chunks of 16B with
// chunk c placed at position c ^ (point&7) (bank-decorrelating swizzle, low-3-bit XOR).
__global__ __launch_bounds__(256) void k1_pre(const float* __restrict__ x, const float* __restrict__ w,
                                              float* __restrict__ sq, float* __restrict__ y,
                                              float* __restrict__ delta, unsigned short* __restrict__ xhl) {
  __shared__ __align__(16) float xt[64][68];
  __shared__ __align__(16) float ws[128][64];
  const int t = threadIdx.x;
  const int bid = blockIdx.x;
  const int b = bid >> 6;
  const int n0 = (bid & 63) << 6;
  const float* xb = x + (size_t)b * 64 * 4096;

#pragma unroll
  for (int rep = 0; rep < 16; ++rep) {
    int id = rep * 256 + t;
    int d = id >> 6, n = id & 63;
    xt[n][d] = xb[(size_t)d * 4096 + n0 + n];
  }
#pragma unroll
  for (int rep = 0; rep < 32; ++rep) {
    int id = rep * 256 + t;
    int u = id >> 6, dd = id & 63;
    ws[u][dd] = w[(u & 63) * 128 + ((u >> 6) << 6) + dd];
  }
  __syncthreads();

  // ---- bf16 hi/lo packed emit: thread t -> point p = t>>2, chunk group cg = t&3 ----
  {
    const int p = t >> 2;
    const int cg = t & 3;
    uint4* orow = (uint4*)xhl + ((size_t)(b << 12) + n0 + p) * 16;
#pragma unroll
    for (int cc = 0; cc < 4; ++cc) {
      const int c = cg * 4 + cc;
      const int kb = (c & 7) * 8;
      const bool lohalf = (c >= 8);
      unsigned int pk[4];
#pragma unroll
      for (int j2 = 0; j2 < 4; ++j2) {
        unsigned short u0, u1;
#pragma unroll
        for (int e = 0; e < 2; ++e) {
          const float xv = xt[p][kb + j2 * 2 + e];
          unsigned short h = bf16_rne(xv);
          unsigned short r;
          if (!lohalf) r = h;
          else r = bf16_rne(xv - __uint_as_float(((unsigned int)h) << 16));
          if (e == 0) u0 = r; else u1 = r;
        }
        pk[j2] = (unsigned int)u0 | ((unsigned int)u1 << 16);
      }
      uint4 v;
      v.x = pk[0]; v.y = pk[1]; v.z = pk[2]; v.w = pk[3];
      orow[c ^ (p & 7)] = v;
    }
  }

  const int p = t & 63;
  const int oc = t >> 6;
  float accy[16], accz[16];
#pragma unroll
  for (int j = 0; j < 16; ++j) { accy[j] = 0.f; accz[j] = 0.f; }

#pragma unroll 4
  for (int d4 = 0; d4 < 16; ++d4) {
    const float4 xv = *(const float4*)&xt[p][d4 * 4];
#pragma unroll
    for (int j = 0; j < 16; ++j) {
      const int o = oc * 16 + j;
      const float4 wy = *(const float4*)&ws[o][d4 * 4];
      const float4 wz = *(const float4*)&ws[o + 64][d4 * 4];
      accy[j] = fmaf(xv.x, wy.x, fmaf(xv.y, wy.y, fmaf(xv.z, wy.z, fmaf(xv.w, wy.w, accy[j]))));
      accz[j] = fmaf(xv.x, wz.x, fmaf(xv.y, wz.y, fmaf(xv.z, wz.z, fmaf(xv.w, wz.w, accz[j]))));
    }
  }

  if (oc == 0) {
    float s = 0.f;
#pragma unroll
    for (int d4 = 0; d4 < 16; ++d4) {
      const float4 v = *(const float4*)&xt[p][d4 * 4];
      s = fmaf(v.x, v.x, fmaf(v.y, v.y, fmaf(v.z, v.z, fmaf(v.w, v.w, s))));
    }
    sq[b * 4096 + n0 + p] = s;
  }

  const size_t row = ((size_t)b * 4096 + n0 + p) * 64 + oc * 16;
#pragma unroll
  for (int j4 = 0; j4 < 4; ++j4) {
    float4 yv = make_float4(accy[j4 * 4], accy[j4 * 4 + 1], accy[j4 * 4 + 2], accy[j4 * 4 + 3]);
    float4 dv = make_float4(accz[j4 * 4] - accy[j4 * 4], accz[j4 * 4 + 1] - accy[j4 * 4 + 1],
                            accz[j4 * 4 + 2] - accy[j4 * 4 + 2], accz[j4 * 4 + 3] - accy[j4 * 4 + 3]);
    *(float4*)&y[row + j4 * 4] = yv;
    *(float4*)&delta[row + j4 * 4] = dv;
  }
}

// ---------------- K2: MFMA pairwise-distance GEMM (bf16 hi/lo) + streaming top-20 ----------------
// R13 = R10 verbatim (best measured: k2 205us, total 314.9us). Session-final state:
//  - R1 macro-structure: 64-n blocks, 4 waves, 32-row m-tiles staged into a slice that
//    doubles as the dump buffer, vmcnt(0) per kt, 48 MFMA/kt, no barriers in the main loop
//  - R9 win (-22us): drain loads hoisted (SoA bufD/bufI[12][256], slot-major, conflict-free;
//    all 24 loads issued up-front -> one latency exposure instead of ~9 dependent round-trips)
//  - R10 win (-10us): parallel shift-insert (comparisons vs the OLD list, dep depth ~3 vs ~60)
//  - thrN[64] shared threshold via LDS atomicMin on float bits; eps 0.001
__global__ __launch_bounds__(256, 2) void k2_knn(const unsigned short* __restrict__ xhl,
                                                 const float* __restrict__ sq,
                                                 int* __restrict__ idx_out) {
  // LDS (float words):
  //  [0,4096)      As 16KB (A rows during prologue) -> bufD[12][256] overlay (3072 words)
  //  [4096,12288)  stage slices: wave w at 4096 + w*2048 (32 m-rows x 256B; doubles as dump)
  //  [12288,15360) bufI[12][256]
  //  [15360,15424) thrN[64] (uint bits of running shared 20th per n)
  //  merge overlay: pf @ [0,5120), pi @ [5120,10240)
  __shared__ __align__(16) float smem[15424];
  const int t = threadIdx.x;
  const int lane = t & 63;
  const int w = t >> 6;
  float* BsW = smem + 4096 + (w << 11);
  uint4* BsW4 = (uint4*)BsW;
  const uint4* As4 = (const uint4*)smem;
  unsigned* bufD = (unsigned*)smem;             // [12][256] overlay on dead As
  unsigned* bufI = (unsigned*)(smem + 12288);   // [12][256]
  unsigned* thrNa = (unsigned*)(smem + 15360);
  volatile unsigned* thrNv = (volatile unsigned*)(smem + 15360);

  const int bid = blockIdx.x;
  const int b = bid >> 6;
  const int n0 = (bid & 63) << 6;
  const int pn = lane & 15, q = lane >> 4;
  const int myn = lane;
  const int swz = myn & 7;

  const unsigned short* xr = xhl + ((size_t)(b << 12)) * 128;
  const float* sqb = sq + (b << 12);

  if (t < 64) thrNa[t] = 0x7F7FFFFFu;  // +BIGF bits (d^2 >= 0: uint order == float order)

  // stage A rows (64 points x 256B = 16KB): 16 x 1KB, 4 per wave
  {
    unsigned short* asu = (unsigned short*)smem;
#pragma unroll
    for (int qq = 0; qq < 4; ++qq) {
      const int kk = w * 4 + qq;
      gload_lds16u(xr + (size_t)n0 * 128 + kk * 512 + lane * 8, asu + kk * 512);
    }
  }
  const float sqn = sqb[n0 + myn];
  __builtin_amdgcn_s_waitcnt(0x0F70);  // vmcnt(0)
  __syncthreads();

  // n-side fragments, register-resident: per nt: [hi0, hi1, lo0, lo1]
  bf16x8 bfr[4][4];
#pragma unroll
  for (int nt = 0; nt < 4; ++nt)
#pragma unroll
    for (int j = 0; j < 4; ++j)
      bfr[nt][j] = *reinterpret_cast<const bf16x8*>(&As4[((nt << 4) + pn) * 16 + (((j << 2) + q) ^ (pn & 7))]);
  __syncthreads();  // all waves done reading As before any accept-buffer write overlays it

  float kd[20];
  int ki[20];
#pragma unroll
  for (int s = 0; s < 20; ++s) { kd[s] = BIGF; ki[s] = -1; }
  int cnt = 0;

  // parallel shift-insert: comparisons all vs the OLD list (independent); s descends so
  // every kd[s-1]/kd[s] read is pre-insert. Semantics identical to the serial carry form.
  auto ins = [&](float vd, int vi) {
#pragma unroll
    for (int s = 19; s >= 1; --s) {
      const bool a = vd < kd[s - 1];
      const bool bb = vd < kd[s];
      kd[s] = a ? kd[s - 1] : (bb ? vd : kd[s]);
      ki[s] = a ? ki[s - 1] : (bb ? vi : ki[s]);
    }
    const bool b0 = vd < kd[0];
    kd[0] = b0 ? vd : kd[0];
    ki[0] = b0 ? vi : ki[0];
  };

  auto drain = [&]() {
    // hoisted, independent, conflict-free loads: one latency exposure for the whole batch
    unsigned vD[12], vI[12];
#pragma unroll
    for (int j = 0; j < 12; ++j) { vD[j] = bufD[j * 256 + t]; vI[j] = bufI[j * 256 + t]; }
#pragma unroll
    for (int j = 0; j < 12; ++j) {
      if (__any(j < cnt)) {
        if (j < cnt) {
          const float dv = __uint_as_float(vD[j]);
          if (dv < kd[19]) ins(dv, (int)vI[j]);
        }
      }
    }
    cnt = 0;
    atomicMin(&thrNa[myn], __float_as_uint(kd[19]));  // publish (monotone decreasing)
  };

  const f32x4 zero4 = {0.f, 0.f, 0.f, 0.f};
  f32x4 acc[4][2];
#pragma unroll
  for (int nt = 0; nt < 4; ++nt) { acc[nt][0] = zero4; acc[nt][1] = zero4; }

  for (int kt = 0; kt < 32; ++kt) {
    const int mbase = (w + 4 * kt) << 5;
    // stage m rows (32 points x 256B = 8KB): 8 x 1KB
    {
      unsigned short* bsu = (unsigned short*)BsW;
      const unsigned short* src = xr + (size_t)mbase * 128;
#pragma unroll
      for (int k = 0; k < 8; ++k) gload_lds16u(src + k * 512 + lane * 8, bsu + k * 512);
    }
    const f32x4 sqm0 = *(const f32x4*)&sqb[mbase + (q << 2)];
    const f32x4 sqm1 = *(const f32x4*)&sqb[mbase + 16 + (q << 2)];
    __builtin_amdgcn_s_waitcnt(0x0F70);  // vmcnt(0)

    // shared per-n gate: single conflict-free read; refreshed again after every drain
    float thr2 = (fminf(__uint_as_float(thrNv[myn]), kd[19]) - sqn) + 0.001f;

#pragma unroll
    for (int mt = 0; mt < 2; ++mt) {
      bf16x8 afr[4];
#pragma unroll
      for (int j = 0; j < 4; ++j)
        afr[j] = *reinterpret_cast<const bf16x8*>(&BsW4[((mt << 4) + pn) * 16 + (((j << 2) + q) ^ (pn & 7))]);
#pragma unroll
      for (int nt = 0; nt < 4; ++nt) {
        f32x4 a = acc[nt][mt];
        a = __builtin_amdgcn_mfma_f32_16x16x32_bf16(afr[0], bfr[nt][0], a, 0, 0, 0);  // hi_m*hi_n
        a = __builtin_amdgcn_mfma_f32_16x16x32_bf16(afr[1], bfr[nt][1], a, 0, 0, 0);
        a = __builtin_amdgcn_mfma_f32_16x16x32_bf16(afr[0], bfr[nt][2], a, 0, 0, 0);  // hi_m*lo_n
        a = __builtin_amdgcn_mfma_f32_16x16x32_bf16(afr[1], bfr[nt][3], a, 0, 0, 0);
        a = __builtin_amdgcn_mfma_f32_16x16x32_bf16(afr[2], bfr[nt][0], a, 0, 0, 0);  // lo_m*hi_n
        a = __builtin_amdgcn_mfma_f32_16x16x32_bf16(afr[3], bfr[nt][1], a, 0, 0, 0);
        acc[nt][mt] = a;
      }
    }

    // dump: value = sq_m - 2*dot, row n, m-quad g=(mt*4+q) at chunk g^(n&7)
#pragma unroll
    for (int nt = 0; nt < 4; ++nt) {
#pragma unroll
      for (int mt = 0; mt < 2; ++mt) {
        const int n = (nt << 4) + pn;
        const int g = (mt << 2) + q;
        const int pc = g ^ (n & 7);
        const f32x4 sv = mt ? sqm1 : sqm0;
        f32x4 dv = sv - 2.0f * acc[nt][mt];
        *(f32x4*)&BsW[(n << 5) + (pc << 2)] = dv;
        acc[nt][mt] = zero4;
      }
    }

    // scan own row (myn): 2 halves x 4 chunks, loads batched 4-at-a-time (latency overlap),
    // v-space min4 pre-gate, accepts -> SoA buffer; thr2 re-tightened after every drain.
    // Ascending-m order + strict < preserves the reference's lowest-index-first tie-break.
#pragma unroll 1
    for (int half = 0; half < 2; ++half) {
      const int cb = half << 2;
      const float4 v0 = *(const float4*)&BsW[(myn << 5) + (((cb + 0) ^ swz) << 2)];
      const float4 v1 = *(const float4*)&BsW[(myn << 5) + (((cb + 1) ^ swz) << 2)];
      const float4 v2 = *(const float4*)&BsW[(myn << 5) + (((cb + 2) ^ swz) << 2)];
      const float4 v3 = *(const float4*)&BsW[(myn << 5) + (((cb + 3) ^ swz) << 2)];
#pragma unroll
      for (int cc = 0; cc < 4; ++cc) {
        const float4 v = (cc == 0) ? v0 : (cc == 1) ? v1 : (cc == 2) ? v2 : v3;
        const int mb = mbase + ((cb + cc) << 2);
        const float mn = fminf(fminf(v.x, v.y), fminf(v.z, v.w));
        if (mn < thr2) {
          if (v.x < thr2) { bufD[cnt * 256 + t] = __float_as_uint(sqn + v.x); bufI[cnt * 256 + t] = (unsigned)mb; cnt++; }
          if (v.y < thr2) { bufD[cnt * 256 + t] = __float_as_uint(sqn + v.y); bufI[cnt * 256 + t] = (unsigned)(mb + 1); cnt++; }
          if (v.z < thr2) { bufD[cnt * 256 + t] = __float_as_uint(sqn + v.z); bufI[cnt * 256 + t] = (unsigned)(mb + 2); cnt++; }
          if (v.w < thr2) { bufD[cnt * 256 + t] = __float_as_uint(sqn + v.w); bufI[cnt * 256 + t] = (unsigned)(mb + 3); cnt++; }
        }
        if (__any(cnt > 8)) {
          drain();  // cap 12: pre<=8, chunk adds <=4
          thr2 = fminf(thr2, (fminf(__uint_as_float(thrNv[myn]), kd[19]) - sqn) + 0.001f);
        }
      }
    }
  }
  drain();

  // merge the 4 waves' partial lists (LDS overlay; bufs/stage dead, thrN untouched)
  __syncthreads();
  float* pf = smem;                 // [4][20][64]
  int* pi = (int*)(smem + 5120);    // [4][20][64]
#pragma unroll
  for (int s = 0; s < 20; ++s) {
    pf[(w * 20 + s) * 64 + lane] = kd[s];
    pi[(w * 20 + s) * 64 + lane] = ki[s];
  }
  __syncthreads();
  if (w == 0) {
    auto insTie = [&](float vd, int vi) {
#pragma unroll
      for (int s = 0; s < 20; ++s) {
        const float od = kd[s];
        const int oi = ki[s];
        const bool lt = (vd < od) || (vd == od && vi < oi);
        kd[s] = lt ? vd : od;
        ki[s] = lt ? vi : oi;
        vd = lt ? od : vd;
        vi = lt ? oi : vi;
      }
    };
    for (int ww = 1; ww < 4; ++ww) {
#pragma unroll 1
      for (int s = 0; s < 20; ++s) {
        const float dv = pf[(ww * 20 + s) * 64 + lane];
        const int iv = pi[(ww * 20 + s) * 64 + lane];
        if (dv < kd[19] || (dv == kd[19] && iv < ki[19])) insTie(dv, iv);
      }
    }
    int* orow = idx_out + ((size_t)(b << 12) + n0 + lane) * 20;
#pragma unroll
    for (int s = 0; s < 20; ++s) orow[s] = ki[s];
  }
}

// ---------------- K3: gathered neighbor max + h + BN stats ----------------
// R13: reverted to the R10-proven form (grid 512, 64 points/block). Both occupancy
// experiments (R11 4x+XCD-remap: +32us; R12 2x sequential: +8us) regressed — the 20
// y-row gathers per point are issued in parallel and L3-resident, so k3 is near its floor.
__global__ __launch_bounds__(256) void k3_gather(const float* __restrict__ y,
                                                 const float* __restrict__ delta,
                                                 const int* __restrict__ idx,
                                                 float* __restrict__ h,
                                                 float* __restrict__ sums,
                                                 float* __restrict__ sumsq) {
  const int t = threadIdx.x;
  const int lane = t & 63;  // channel o
  const int w = t >> 6;
  const int blk = blockIdx.x;
  float s1 = 0.f, s2 = 0.f;
  for (int p = 0; p < 16; ++p) {
    const int ng = blk * 64 + w * 16 + p;
    const int b = ng >> 12;
    const int* row = idx + (size_t)ng * 20;
    float mx = -BIGF;
#pragma unroll
    for (int kk = 0; kk < 20; ++kk) {
      const int nbr = row[kk];
      mx = fmaxf(mx, y[((size_t)(b << 12) + nbr) * 64 + lane]);
    }
    const float hv = mx + delta[(size_t)ng * 64 + lane];
    h[(size_t)ng * 64 + lane] = hv;
    s1 += hv;
    s2 += hv * hv;
  }
  __shared__ float r1[4][64], r2[4][64];
  r1[w][lane] = s1;
  r2[w][lane] = s2;
  __syncthreads();
  if (w == 0) {
    const float a = r1[0][lane] + r1[1][lane] + r1[2][lane] + r1[3][lane];
    const float c = r2[0][lane] + r2[1][lane] + r2[2][lane] + r2[3][lane];
    atomicAdd(&sums[lane], a);
    atomicAdd(&sumsq[lane], c);
  }
}

// ---------------- K4: BN finalize + exact GELU + transposed write ----------------
__global__ __launch_bounds__(256) void k4_bn(const float* __restrict__ h,
                                             const float* __restrict__ sums,
                                             const float* __restrict__ sumsq,
                                             const float* __restrict__ gamma,
                                             const float* __restrict__ beta,
                                             float* __restrict__ out) {
  __shared__ float tile[64][65];
  const int bid = blockIdx.x;
  const int b = bid >> 6;
  const int n0 = (bid & 63) << 6;
  const int t = threadIdx.x;
  const int o = t & 63;
#pragma unroll
  for (int it = 0; it < 16; ++it) {
    const int n = (t >> 6) * 16 + it;
    tile[n][o] = h[(((size_t)b << 12) + n0 + n) * 64 + o];
  }
  __syncthreads();
  const int j = t & 63;
#pragma unroll
  for (int it = 0; it < 16; ++it) {
    const int oo = (t >> 6) * 16 + it;
    const float mean = sums[oo] * (1.0f / 32768.0f);
    const float var = sumsq[oo] * (1.0f / 32768.0f) - mean * mean;
    const float sc = gamma[oo] / sqrtf(var + 1e-5f);
    const float hv = tile[j][oo];
    const float hn = (hv - mean) * sc + beta[oo];
    const float g = 0.5f * hn * (1.0f + erff(hn * 0.70710678118654752f));
    out[((size_t)(b * 64 + oo)) * 4096 + n0 + j] = g;
  }
}

extern "C" void kernel_launch(void* const* d_in, const int* in_sizes, int n_in,
                              void* d_out, int out_size, void* d_ws, size_t ws_size,
                              hipStream_t stream) {
  const float* x = (const float*)d_in[0];
  const float* w = (const float*)d_in[1];
  const float* gamma = (const float*)d_in[2];
  const float* beta = (const float*)d_in[3];
  float* out = (float*)d_out;

  float* sq_ws = (float*)d_ws;               // 32768
  float* y_ws = sq_ws + 32768;               // 8 MB
  float* delta_ws = y_ws + 2097152;          // 8 MB
  float* h_ws = delta_ws + 2097152;          // 8 MB (k3/k4) — overlaid by xhl in k1/k2
  int* idx_ws = (int*)(h_ws + 2097152);      // 2.6 MB
  float* sums = (float*)(idx_ws + 655360);   // 64
  float* sumsq = sums + 64;                  // 64
  unsigned short* xhl = (unsigned short*)h_ws;  // 8 MB bf16 hi/lo rows (dead after k2)

  hipMemsetAsync(sums, 0, 2 * 64 * sizeof(float), stream);
  k1_pre<<<512, 256, 0, stream>>>(x, w, sq_ws, y_ws, delta_ws, xhl);
  k2_knn<<<512, 256, 0, stream>>>(xhl, sq_ws, idx_ws);
  k3_gather<<<512, 256, 0, stream>>>(y_ws, delta_ws, idx_ws, h_ws, sums, sumsq);
  k4_bn<<<512, 256, 0, stream>>>(h_ws, sums, sumsq, gamma, beta, out);
}